// Round 3
// baseline (232.647 us; speedup 1.0000x reference)
//
#include <hip/hip_runtime.h>
#include <math.h>

// LayerNorm(Re(FFT(x, axis=-1))), x: (B=4, N=4096, C=2048) fp32.
// One 256-thread block per PAIR of rows: z = x_even + i*x_odd.
// Mixed-radix Stockham FFT: 3 radix-8 stages + 1 twiddle-free radix-4 stage,
// SINGLE padded LDS buffer (read -> barrier -> write -> barrier per stage),
// stage 1 reads global directly. 18.5 KB LDS -> 8 blocks/CU (32 waves).

#define TPB 256
#define CD  2048
#define PAD(j) ((j) + ((j) >> 3))

__device__ __forceinline__ float2 f2add(float2 a, float2 b) { return make_float2(a.x + b.x, a.y + b.y); }
__device__ __forceinline__ float2 f2sub(float2 a, float2 b) { return make_float2(a.x - b.x, a.y - b.y); }
__device__ __forceinline__ float2 cmul(float2 a, float2 b) {
    return make_float2(a.x * b.x - a.y * b.y, a.x * b.y + a.y * b.x);
}

// Radix-8 DFT of x[0..7] + twiddle W_{N_}^(p*r) + store, N_ = 2048/S_.
// Stockham: q = t mod S_, p = t div S_, dst[q + 8*S_*p + r*S_].
template<int S_>
__device__ __forceinline__ void r8_store(float2* buf, int t, const float2* x)
{
    float2 a0 = f2add(x[0], x[4]), a1 = f2add(x[1], x[5]);
    float2 a2 = f2add(x[2], x[6]), a3 = f2add(x[3], x[7]);
    float2 b0 = f2sub(x[0], x[4]), b1 = f2sub(x[1], x[5]);
    float2 b2 = f2sub(x[2], x[6]), b3 = f2sub(x[3], x[7]);
    // even outputs: DFT4(a) with w4 = -i
    float2 c0 = f2add(a0, a2), c1 = f2sub(a0, a2);
    float2 d0 = f2add(a1, a3), d1 = f2sub(a1, a3);
    float2 X0 = f2add(c0, d0), X4 = f2sub(c0, d0);
    float2 X2 = make_float2(c1.x + d1.y, c1.y - d1.x);   // c1 - i*d1
    float2 X6 = make_float2(c1.x - d1.y, c1.y + d1.x);   // c1 + i*d1
    // odd outputs: y_k = b_k * w8^k, then DFT4(y)
    const float R2 = 0.70710678118654752440f;
    float2 y1 = make_float2((b1.x + b1.y) * R2, (b1.y - b1.x) * R2);   // *(1-i)/sqrt2
    float2 y2 = make_float2(b2.y, -b2.x);                              // *(-i)
    float2 y3 = make_float2((b3.y - b3.x) * R2, -(b3.x + b3.y) * R2);  // *-(1+i)/sqrt2
    float2 e0 = f2add(b0, y2), e1p = f2sub(b0, y2);
    float2 f0 = f2add(y1, y3), f1 = f2sub(y1, y3);
    float2 X1 = f2add(e0, f0), X5 = f2sub(e0, f0);
    float2 X3 = make_float2(e1p.x + f1.y, e1p.y - f1.x); // e1p - i*f1
    float2 X7 = make_float2(e1p.x - f1.y, e1p.y + f1.x); // e1p + i*f1

    const int q = t & (S_ - 1);
    const int p = t / S_;
    const float th = -6.28318530717958647692f * (float)S_ / 2048.0f;  // -2pi/N_
    float sw, cw;
    __sincosf(th * (float)p, &sw, &cw);
    const float2 e1 = make_float2(cw, sw);
    const int o = q + 8 * S_ * p;
    buf[PAD(o)] = X0;
    float2 cur = e1;
    buf[PAD(o + 1 * S_)] = cmul(X1, cur); cur = cmul(cur, e1);
    buf[PAD(o + 2 * S_)] = cmul(X2, cur); cur = cmul(cur, e1);
    buf[PAD(o + 3 * S_)] = cmul(X3, cur); cur = cmul(cur, e1);
    buf[PAD(o + 4 * S_)] = cmul(X4, cur); cur = cmul(cur, e1);
    buf[PAD(o + 5 * S_)] = cmul(X5, cur); cur = cmul(cur, e1);
    buf[PAD(o + 6 * S_)] = cmul(X6, cur); cur = cmul(cur, e1);
    buf[PAD(o + 7 * S_)] = cmul(X7, cur);
}

__global__ __launch_bounds__(TPB, 8) void fourier_ln_kernel(
    const float* __restrict__ x,
    const float* __restrict__ gamma,
    const float* __restrict__ beta,
    float* __restrict__ out)
{
    __shared__ float2 buf[2304];   // PAD(2047)=2302 -> 2304 float2 = 18432 B
    __shared__ float red[16];
    __shared__ float bc[4];

    const int t = threadIdx.x;
    const long long row0 = 2LL * (long long)blockIdx.x;
    const long long row1 = row0 + 1;
    const float* xr = x + row0 * CD;
    const float* xi = x + row1 * CD;

    // ---- stage 1 (S=1, N=2048): read global (coalesced), butterfly, write LDS
    {
        float2 v[8];
#pragma unroll
        for (int k = 0; k < 8; k++)
            v[k] = make_float2(xr[t + 256 * k], xi[t + 256 * k]);
        r8_store<1>(buf, t, v);
    }
    __syncthreads();

    // ---- stage 2 (S=8, N=256)
    {
        float2 v[8];
#pragma unroll
        for (int k = 0; k < 8; k++) v[k] = buf[PAD(t + 256 * k)];
        __syncthreads();
        r8_store<8>(buf, t, v);
    }
    __syncthreads();

    // ---- stage 3 (S=64, N=32)
    {
        float2 v[8];
#pragma unroll
        for (int k = 0; k < 8; k++) v[k] = buf[PAD(t + 256 * k)];
        __syncthreads();
        r8_store<64>(buf, t, v);
    }
    __syncthreads();

    // ---- stage 4 (radix-4, S=512, p=0 -> twiddle-free): Z in natural order
    {
        float2 w[8];
#pragma unroll
        for (int h = 0; h < 2; h++)
#pragma unroll
            for (int k = 0; k < 4; k++)
                w[4 * h + k] = buf[PAD(t + 256 * h + 512 * k)];
        __syncthreads();
#pragma unroll
        for (int h = 0; h < 2; h++) {
            float2 c0 = f2add(w[4 * h + 0], w[4 * h + 2]);
            float2 c1 = f2sub(w[4 * h + 0], w[4 * h + 2]);
            float2 d0 = f2add(w[4 * h + 1], w[4 * h + 3]);
            float2 d1 = f2sub(w[4 * h + 1], w[4 * h + 3]);
            const int b = t + 256 * h;
            buf[PAD(b)]        = f2add(c0, d0);
            buf[PAD(b + 512)]  = make_float2(c1.x + d1.y, c1.y - d1.x);
            buf[PAD(b + 1024)] = f2sub(c0, d0);
            buf[PAD(b + 1536)] = make_float2(c1.x - d1.y, c1.y + d1.x);
        }
    }
    __syncthreads();

    // ---- untangle + moments. k owned as 4t+c (+1024*jj) for float4 I/O.
    // Re X0[k] = (ReZ[k]+ReZ[N-k])/2, Re X1[k] = (ImZ[k]+ImZ[N-k])/2.
    float y0v[8], y1v[8];
    float s0 = 0.f, ss0 = 0.f, s1 = 0.f, ss1 = 0.f;
#pragma unroll
    for (int jj = 0; jj < 2; jj++) {
#pragma unroll
        for (int c = 0; c < 4; c++) {
            int k = 4 * t + c + 1024 * jj;
            float2 zk = buf[PAD(k)];
            float2 zr = buf[PAD((CD - k) & (CD - 1))];
            float a = 0.5f * (zk.x + zr.x);
            float b = 0.5f * (zk.y + zr.y);
            y0v[4 * jj + c] = a; y1v[4 * jj + c] = b;
            s0 += a; ss0 += a * a;
            s1 += b; ss1 += b * b;
        }
    }

    // ---- block reduce (wave-64 shuffle -> LDS partials)
#pragma unroll
    for (int off = 32; off > 0; off >>= 1) {
        s0  += __shfl_down(s0,  off, 64);
        ss0 += __shfl_down(ss0, off, 64);
        s1  += __shfl_down(s1,  off, 64);
        ss1 += __shfl_down(ss1, off, 64);
    }
    const int wave = t >> 6;
    if ((t & 63) == 0) {
        red[4 * wave + 0] = s0;
        red[4 * wave + 1] = ss0;
        red[4 * wave + 2] = s1;
        red[4 * wave + 3] = ss1;
    }
    __syncthreads();
    if (t == 0) {
        float S0 = 0.f, SS0 = 0.f, S1 = 0.f, SS1 = 0.f;
#pragma unroll
        for (int w = 0; w < 4; w++) {
            S0 += red[4 * w + 0]; SS0 += red[4 * w + 1];
            S1 += red[4 * w + 2]; SS1 += red[4 * w + 3];
        }
        const float inv = 1.0f / (float)CD;
        float mu0 = S0 * inv, mu1 = S1 * inv;
        float v0 = SS0 * inv - mu0 * mu0;
        float v1 = SS1 * inv - mu1 * mu1;
        bc[0] = mu0; bc[1] = rsqrtf(v0 + 1e-5f);
        bc[2] = mu1; bc[3] = rsqrtf(v1 + 1e-5f);
    }
    __syncthreads();
    const float mu0 = bc[0], r0 = bc[1];
    const float mu1 = bc[2], r1 = bc[3];

    // ---- normalize + gamma/beta, float4 I/O
    const float4* g4 = (const float4*)gamma;
    const float4* b4 = (const float4*)beta;
    float4* o0 = (float4*)(out + row0 * CD);
    float4* o1 = (float4*)(out + row1 * CD);
#pragma unroll
    for (int jj = 0; jj < 2; jj++) {
        int idx = t + 256 * jj;
        float4 g = g4[idx];
        float4 be = b4[idx];
        float4 r0v, r1v;
        r0v.x = (y0v[4 * jj + 0] - mu0) * r0 * g.x + be.x;
        r0v.y = (y0v[4 * jj + 1] - mu0) * r0 * g.y + be.y;
        r0v.z = (y0v[4 * jj + 2] - mu0) * r0 * g.z + be.z;
        r0v.w = (y0v[4 * jj + 3] - mu0) * r0 * g.w + be.w;
        r1v.x = (y1v[4 * jj + 0] - mu1) * r1 * g.x + be.x;
        r1v.y = (y1v[4 * jj + 1] - mu1) * r1 * g.y + be.y;
        r1v.z = (y1v[4 * jj + 2] - mu1) * r1 * g.z + be.z;
        r1v.w = (y1v[4 * jj + 3] - mu1) * r1 * g.w + be.w;
        o0[idx] = r0v;
        o1[idx] = r1v;
    }
}

extern "C" void kernel_launch(void* const* d_in, const int* in_sizes, int n_in,
                              void* d_out, int out_size, void* d_ws, size_t ws_size,
                              hipStream_t stream) {
    (void)in_sizes; (void)n_in; (void)d_ws; (void)ws_size; (void)out_size;
    const float* x     = (const float*)d_in[0];
    const float* gamma = (const float*)d_in[1];
    const float* beta  = (const float*)d_in[2];
    float* out = (float*)d_out;

    const int total_rows = 4 * 4096;           // B * N
    const int blocks = total_rows / 2;         // one block per row pair
    fourier_ln_kernel<<<blocks, TPB, 0, stream>>>(x, gamma, beta, out);
}